// Round 9
// baseline (609.090 us; speedup 1.0000x reference)
//
#include <hip/hip_runtime.h>

#define TOK 8192   // B*S
#define DIM 512    // D
#define NE  32     // experts
#define KTOT (NE * DIM)

#define BM 128
#define BN 64
#define BK 64

typedef float f32x4 __attribute__((ext_vector_type(4)));
typedef short s16x8 __attribute__((ext_vector_type(8)));

typedef const void __attribute__((address_space(1)))* gp1_t;
typedef void __attribute__((address_space(3)))* lp3_t;

__device__ __forceinline__ void gl_lds16(const void* g, void* l) {
    __builtin_amdgcn_global_load_lds((gp1_t)g, (lp3_t)l, 16, 0, 0);
}

__device__ __forceinline__ ushort f2bf(float f) {
    unsigned u = __builtin_bit_cast(unsigned, f);
    unsigned r = (u + 0x7fffu + ((u >> 16) & 1u)) >> 16;
    return (ushort)r;
}

__device__ __forceinline__ float bf2f(ushort u) {
    return __builtin_bit_cast(float, (unsigned)u << 16);
}

// ---- fused prep: blocks [0,2048) transpose+convert W; [2048,3072) gates+cvt x
// Gates written TRANSPOSED and in bf16: G2b[e][tok].
__global__ __launch_bounds__(256) void k_prep(const float* __restrict__ w,
                                              ushort* __restrict__ wt,
                                              const float* __restrict__ x,
                                              const float* __restrict__ gw,
                                              const float* __restrict__ gb,
                                              ushort* __restrict__ G2b,
                                              ushort* __restrict__ xb) {
    __shared__ __align__(16) char smem[64 * 65 * 4];
    const int bx = blockIdx.x;
    const int tid = threadIdx.x;
    if (bx < 2048) {
        float (*tile)[65] = (float(*)[65])smem;
        const int e = bx >> 6;
        const int f0 = ((bx >> 3) & 7) * 64;
        const int d0 = (bx & 7) * 64;
        const int tx = tid & 63, ty = tid >> 6;  // ty 0..3
        const float* we = w + (size_t)e * DIM * DIM;
#pragma unroll
        for (int i = ty; i < 64; i += 4)
            tile[i][tx] = we[(size_t)(d0 + i) * DIM + f0 + tx];
        __syncthreads();
#pragma unroll
        for (int i = ty; i < 64; i += 4)
            wt[(size_t)(f0 + i) * KTOT + e * DIM + d0 + tx] = f2bf(tile[tx][i]);
    } else {
        float* xs = (float*)smem;
        const int t0 = (bx - 2048) * 8;
        const float* xBase = x + (size_t)t0 * DIM;
#pragma unroll
        for (int k = 0; k < 4; ++k) {
            int i4 = (k * 256 + tid) * 4;
            float4 v = *(const float4*)(xBase + i4);
            xs[i4 + 0] = v.x; xs[i4 + 1] = v.y; xs[i4 + 2] = v.z; xs[i4 + 3] = v.w;
            ushort4 o;
            o.x = f2bf(v.x); o.y = f2bf(v.y); o.z = f2bf(v.z); o.w = f2bf(v.w);
            *(ushort4*)(xb + (size_t)t0 * DIM + i4) = o;
        }
        __syncthreads();
        const int tok = tid >> 5;   // 0..7
        const int e = tid & 31;
        float l = gb[e];
        const float* xr = xs + tok * DIM;
#pragma unroll 8
        for (int d = 0; d < DIM; ++d)
            l += xr[d] * gw[d * NE + e];
        float mx = l;
#pragma unroll
        for (int m = 16; m >= 1; m >>= 1) mx = fmaxf(mx, __shfl_xor(mx, m));
        float ex = expf(l - mx);
        float s = ex;
#pragma unroll
        for (int m = 16; m >= 1; m >>= 1) s += __shfl_xor(s, m);
        G2b[(size_t)e * TOK + t0 + tok] = f2bf(ex / s);
    }
}

// -------- main GEMM v4: ee-outer / kt-pair-inner, fold once per expert -----
// Block 128x64, 4 waves of 64x32. 64 barrier intervals (was 128): each
// processes 2 K-tiles (32 MFMAs/wave) of one expert from a 16 KB LDS tile
// pair (dbuf, one-ahead DMA). A-frags in VGPRs straight from global (L2-hot
// xb), issued BEFORE the DMA so their vmcnt wait leaves the DMA in flight.
// pacc persists across one expert's 4 intervals; gate fold once per expert
// (16x fewer LDS gate reads; gates bf16, Gs = 4 KB). z=2 expert split.
__global__ __launch_bounds__(256, 4) void k_moe_gemm(const ushort* __restrict__ xb,
                                                     const ushort* __restrict__ wt,
                                                     const ushort* __restrict__ G2b,
                                                     float* __restrict__ out0,
                                                     float* __restrict__ out1) {
    __shared__ __align__(16) ushort Bs[2][2][BN * BK];   // [buf][ktHalf] 32 KB
    __shared__ ushort Gs[16][BM];                        // 4 KB bf16 gates

    const int tid = threadIdx.x;
    const int m0 = blockIdx.y * BM;
    const int n0 = blockIdx.x * BN;
    const int e0 = blockIdx.z * 16;
    float* __restrict__ dst = blockIdx.z ? out1 : out0;

    for (int i = tid; i < 16 * BM; i += 256)
        Gs[i >> 7][i & 127] = G2b[(size_t)(e0 + (i >> 7)) * TOK + m0 + (i & 127)];

    const int lane = tid & 63;
    const int wave = tid >> 6;            // 0..3
    const int wm = (wave & 1) * 64;
    const int wn = (wave >> 1) * 32;
    const int l15 = lane & 15;
    const int q = lane >> 4;              // 0..3
    const int keyR = l15 & 7;

    // B reader byte offsets within a tile: row*128 + ((ks*4+q)^key)*16
    int rb[2][2];
#pragma unroll
    for (int j = 0; j < 2; ++j)
#pragma unroll
        for (int ks = 0; ks < 2; ++ks)
            rb[j][ks] = (wn + j * 16 + l15) * 128 + (((ks * 4 + q) ^ keyR) << 4);

    // staging map (8 KB tile = 256 thr x 2 chunks; rows 0..31 then 32..63)
    const int srow = tid >> 3;                       // 0..31
    const int c8 = tid & 7;
    const int scol = ((c8 ^ (srow & 7)) * 8);        // swizzled global column
    const ushort* bBase = wt + (size_t)(n0 + srow) * KTOT + (size_t)e0 * DIM + scol;
    const int ldsOff = tid * 16;

    // A fragment pointers
    const ushort* aP[4];
#pragma unroll
    for (int i = 0; i < 4; ++i)
        aP[i] = xb + (size_t)(m0 + wm + i * 16 + l15) * DIM + q * 8;

    const f32x4 zv = {0.f, 0.f, 0.f, 0.f};
    f32x4 acc[4][2];
#pragma unroll
    for (int i = 0; i < 4; ++i)
#pragma unroll
        for (int j = 0; j < 2; ++j) acc[i][j] = zv;

    // prologue: DMA pair p=0 (ee=0, kt=0,1) into buf 0
#pragma unroll
    for (int t = 0; t < 2; ++t) {
        const ushort* src = bBase + t * BK;
        gl_lds16(src, (char*)Bs[0][t] + ldsOff);
        gl_lds16(src + (size_t)32 * KTOT, (char*)Bs[0][t] + 4096 + ldsOff);
    }
    __syncthreads();

#pragma unroll 1
    for (int ee = 0; ee < 16; ++ee) {
        f32x4 pacc[4][2];
#pragma unroll
        for (int i = 0; i < 4; ++i)
#pragma unroll
            for (int j = 0; j < 2; ++j) pacc[i][j] = zv;

#pragma unroll 1
        for (int kp = 0; kp < 4; ++kp) {
            const int p = ee * 4 + kp;
            const int kt0 = kp * 2;

            // A frags for kt0 (global; issued before DMA so vmcnt wait
            // for them does not drain the prefetch)
            s16x8 a[4][2];
#pragma unroll
            for (int i = 0; i < 4; ++i) {
                a[i][0] = *(const s16x8*)(aP[i] + kt0 * 64);
                a[i][1] = *(const s16x8*)(aP[i] + kt0 * 64 + 32);
            }

            // one-ahead DMA of the next tile pair
            if (p + 1 < 64) {
                const int en = (p + 1) >> 2;
                const int kpn = (p + 1) & 3;
                char* bl = (char*)Bs[(p + 1) & 1];
#pragma unroll
                for (int t = 0; t < 2; ++t) {
                    const ushort* src = bBase + (size_t)en * DIM + (kpn * 2 + t) * BK;
                    gl_lds16(src, bl + t * 8192 + ldsOff);
                    gl_lds16(src + (size_t)32 * KTOT, bl + t * 8192 + 4096 + ldsOff);
                }
            }

            // compute kt0 from tile [p&1][0]
            {
                const char* Bb = (const char*)Bs[p & 1][0];
#pragma unroll
                for (int ks = 0; ks < 2; ++ks) {
                    s16x8 b0 = *(const s16x8*)(Bb + rb[0][ks]);
                    s16x8 b1 = *(const s16x8*)(Bb + rb[1][ks]);
#pragma unroll
                    for (int i = 0; i < 4; ++i) {
                        pacc[i][0] = __builtin_amdgcn_mfma_f32_16x16x32_bf16(
                            a[i][ks], b0, pacc[i][0], 0, 0, 0);
                        pacc[i][1] = __builtin_amdgcn_mfma_f32_16x16x32_bf16(
                            a[i][ks], b1, pacc[i][1], 0, 0, 0);
                    }
                }
            }

            // A frags for kt1, then compute from tile [p&1][1]
#pragma unroll
            for (int i = 0; i < 4; ++i) {
                a[i][0] = *(const s16x8*)(aP[i] + kt0 * 64 + 64);
                a[i][1] = *(const s16x8*)(aP[i] + kt0 * 64 + 96);
            }
            {
                const char* Bb = (const char*)Bs[p & 1][1];
#pragma unroll
                for (int ks = 0; ks < 2; ++ks) {
                    s16x8 b0 = *(const s16x8*)(Bb + rb[0][ks]);
                    s16x8 b1 = *(const s16x8*)(Bb + rb[1][ks]);
#pragma unroll
                    for (int i = 0; i < 4; ++i) {
                        pacc[i][0] = __builtin_amdgcn_mfma_f32_16x16x32_bf16(
                            a[i][ks], b0, pacc[i][0], 0, 0, 0);
                        pacc[i][1] = __builtin_amdgcn_mfma_f32_16x16x32_bf16(
                            a[i][ks], b1, pacc[i][1], 0, 0, 0);
                    }
                }
            }
            __syncthreads();   // publishes next buffer; DMA had a full interval
        }

        // fold this expert into master acc (once per expert)
#pragma unroll
        for (int i = 0; i < 4; ++i) {
            const ushort4 gu = *(const ushort4*)&Gs[ee][wm + i * 16 + q * 4];
            const float g0 = bf2f(gu.x), g1 = bf2f(gu.y);
            const float g2 = bf2f(gu.z), g3 = bf2f(gu.w);
#pragma unroll
            for (int j = 0; j < 2; ++j) {
                acc[i][j][0] += g0 * pacc[i][j][0];
                acc[i][j][1] += g1 * pacc[i][j][1];
                acc[i][j][2] += g2 * pacc[i][j][2];
                acc[i][j][3] += g3 * pacc[i][j][3];
            }
        }
    }

    // epilogue: plain stores (each element owned by exactly one lane)
#pragma unroll
    for (int i = 0; i < 4; ++i) {
        const int tl = m0 + wm + i * 16 + q * 4;
#pragma unroll
        for (int j = 0; j < 2; ++j) {
            const int f = n0 + wn + j * 16 + l15;
            float* p = dst + (size_t)tl * DIM + f;
            p[0 * DIM] = acc[i][j][0];
            p[1 * DIM] = acc[i][j][1];
            p[2 * DIM] = acc[i][j][2];
            p[3 * DIM] = acc[i][j][3];
        }
    }
}

// ---- deterministic two-phase sum: out += P (both fully written upstream) ----
__global__ __launch_bounds__(256) void k_reduce(float* __restrict__ out,
                                                const float* __restrict__ P) {
    int i = (blockIdx.x * 256 + threadIdx.x) * 4;
    float4 a = *(const float4*)(out + i);
    float4 b = *(const float4*)(P + i);
    a.x += b.x; a.y += b.y; a.z += b.z; a.w += b.w;
    *(float4*)(out + i) = a;
}

extern "C" void kernel_launch(void* const* d_in, const int* in_sizes, int n_in,
                              void* d_out, int out_size, void* d_ws, size_t ws_size,
                              hipStream_t stream) {
    const float* x  = (const float*)d_in[0];   // [8192][512]
    const float* gw = (const float*)d_in[1];   // [512][32]
    const float* gb = (const float*)d_in[2];   // [32]
    const float* w  = (const float*)d_in[3];   // [32][512][512]
    float* out = (float*)d_out;                // [8192][512] fp32

    char* ws = (char*)d_ws;
    ushort* xb  = (ushort*)ws;                           //  0..8 MiB
    ushort* wt  = (ushort*)(ws + (8u << 20));            //  8..24 MiB
    ushort* G2b = (ushort*)(ws + (24u << 20));           // 24..25 MiB ([e][tok] bf16)
    float*  P   = (float*)(ws + (25u << 20));            // 25..41 MiB

    k_prep<<<dim3(2048 + TOK / 8), dim3(256), 0, stream>>>(w, wt, x, gw, gb, G2b, xb);
    k_moe_gemm<<<dim3(DIM / BN, TOK / BM, 2), dim3(256), 0, stream>>>(xb, wt, G2b, out, P);
    k_reduce<<<dim3(TOK * DIM / 1024), dim3(256), 0, stream>>>(out, P);
}